// Round 10
// baseline (232.027 us; speedup 1.0000x reference)
//
#include <hip/hip_runtime.h>
#include <math.h>

#define RMAX 4.0f
#define NTAB 4096    // intervals over [0,4); rows 0..4096 built (+pad)
#define DEGCAP 48    // max live in-degree bucket capacity (P(exceed) ~ 1e-11)

__device__ __forceinline__ float tanh_fast(float x){
  float e = __expf(2.0f * x);
  return 1.0f - 2.0f / (e + 1.0f);
}
__device__ __forceinline__ float normact(float s){
  float ns = fabsf(s);
  return s * tanh_fast(ns) / (ns + 1e-8f);
}

// ---------------- precompute per-species tables ----------------
__global__ void k_pre(const float* __restrict__ Wna, const float* __restrict__ Wlin1,
                      const float* __restrict__ Wsc,
                      float* __restrict__ x1tab, float* __restrict__ sctab){
  int id = threadIdx.x;
  if (id < 128){
    int c = id >> 5, j = id & 31;
    float acc = 0.f;
    for (int i = 0; i < 32; ++i) acc += Wna[c*32+i] * Wlin1[i*32+j];
    x1tab[id] = acc * (0.5f * 0.17677669529663687f);
  }
  if (id < 256){
    int c = id >> 6, k = id & 63;
    float acc = 0.f;
    for (int i = 0; i < 32; ++i) acc += Wna[c*32+i] * Wsc[(i*4+c)*64+k];
    sctab[id] = acc * (0.5f * 0.08838834764831843f);
  }
}

// ---------------- build radial table: tab[(i*4+c)*32+g] = w(r_i)[g]*x1tab[c][g] ----
__global__ void __launch_bounds__(256) k_tab(
    const float* __restrict__ Wr1, const float* __restrict__ Wr2,
    const float* __restrict__ Wr3, const float* __restrict__ x1tab,
    float* __restrict__ tab){
  __shared__ float sW1[8*64];
  __shared__ float sW2T[64*64];
  __shared__ float sW3[64*32];
  __shared__ float sX1[4*32];
  int t = threadIdx.x;
  for (int i = t; i < 512; i += 256) sW1[i] = Wr1[i] * 0.3535533905932738f;
  for (int i = t; i < 4096; i += 256){ int rr = i >> 6, cc = i & 63; sW2T[cc*64+rr] = Wr2[i] * 0.125f; }
  for (int i = t; i < 2048; i += 256){ int rr = i >> 5, cc = i & 31; sW3[i] = Wr3[rr*64+cc] * 0.125f; }
  for (int i = t; i < 128; i += 256) sX1[i] = x1tab[i];
  __syncthreads();
  int i = blockIdx.x * 256 + t;
  if (i > NTAB) return;
  float r = fmaxf((float)i * (RMAX / (float)NTAB), 1e-6f);

  float u = r * 0.25f;
  float u2 = u*u, u4 = u2*u2, u6 = u4*u2;
  float fc = 1.0f + u6 * (-28.0f + u * (48.0f - 21.0f * u));
  float pref = 0.5f / r * fc;
  float ea[8];
  #pragma unroll
  for (int k = 1; k <= 8; ++k) ea[k-1] = __sinf(0.78539816339744831f * r * (float)k) * pref;

  float h1[64];
  #pragma unroll
  for (int j = 0; j < 64; j += 4){
    float ax = 0.f, ay = 0.f, az = 0.f, aw = 0.f;
    #pragma unroll
    for (int k = 0; k < 8; ++k){
      const float4 w4 = *(const float4*)&sW1[k*64 + j];
      ax += ea[k]*w4.x; ay += ea[k]*w4.y; az += ea[k]*w4.z; aw += ea[k]*w4.w;
    }
    h1[j]   = tanh_fast(ax); h1[j+1] = tanh_fast(ay);
    h1[j+2] = tanh_fast(az); h1[j+3] = tanh_fast(aw);
  }

  float wsx[8], wsy[8], wsz[8], wsw[8];
  #pragma unroll
  for (int g = 0; g < 8; ++g){ wsx[g]=0.f; wsy[g]=0.f; wsz[g]=0.f; wsw[g]=0.f; }
  for (int j = 0; j < 64; ++j){
    float ax = 0.f, ay = 0.f, az = 0.f, aw = 0.f;
    #pragma unroll
    for (int k = 0; k < 64; k += 4){
      const float4 w4 = *(const float4*)&sW2T[j*64 + k];
      ax += h1[k]*w4.x; ay += h1[k+1]*w4.y; az += h1[k+2]*w4.z; aw += h1[k+3]*w4.w;
    }
    float tj = tanh_fast(ax + ay + az + aw);
    #pragma unroll
    for (int g = 0; g < 8; ++g){
      const float4 w4 = *(const float4*)&sW3[j*32 + g*4];
      wsx[g] += tj*w4.x; wsy[g] += tj*w4.y; wsz[g] += tj*w4.z; wsw[g] += tj*w4.w;
    }
  }

  #pragma unroll
  for (int c = 0; c < 4; ++c){
    float* row = tab + ((size_t)i*4 + c)*32;
    #pragma unroll
    for (int g = 0; g < 8; ++g){
      const float4 xv = *(const float4*)&sX1[c*32 + g*4];
      row[g*4+0] = wsx[g]*xv.x;
      row[g*4+1] = wsy[g]*xv.y;
      row[g*4+2] = wsz[g]*xv.z;
      row[g*4+3] = wsw[g]*xv.w;
    }
  }
}

// ---------------- single-pass bucketed edge build (4 edges/thread for ILP) ----
// pay[d*DEGCAP + slot] = r packed with species(src) in low 2 bits
__global__ void __launch_bounds__(256) k_edges(
    const float* __restrict__ coords, const int* __restrict__ ei,
    const int* __restrict__ species, int* __restrict__ hist,
    unsigned* __restrict__ pay, int E){
  int t0 = blockIdx.x * 1024 + threadIdx.x;
  int i0 = t0, i1 = t0 + 256, i2 = t0 + 512, i3 = t0 + 768;
  bool v0 = i0 < E, v1 = i1 < E, v2 = i2 < E, v3 = i3 < E;
  int s0 = v0 ? ei[i0] : 0, d0 = v0 ? ei[E+i0] : 0;
  int s1 = v1 ? ei[i1] : 0, d1 = v1 ? ei[E+i1] : 0;
  int s2 = v2 ? ei[i2] : 0, d2 = v2 ? ei[E+i2] : 0;
  int s3 = v3 ? ei[i3] : 0, d3 = v3 ? ei[E+i3] : 0;
  float3 a0 = v0 ? *(const float3*)(coords+3*s0) : make_float3(0,0,0);
  float3 b0 = v0 ? *(const float3*)(coords+3*d0) : make_float3(9,9,9);
  float3 a1 = v1 ? *(const float3*)(coords+3*s1) : make_float3(0,0,0);
  float3 b1 = v1 ? *(const float3*)(coords+3*d1) : make_float3(9,9,9);
  float3 a2 = v2 ? *(const float3*)(coords+3*s2) : make_float3(0,0,0);
  float3 b2 = v2 ? *(const float3*)(coords+3*d2) : make_float3(9,9,9);
  float3 a3 = v3 ? *(const float3*)(coords+3*s3) : make_float3(0,0,0);
  float3 b3 = v3 ? *(const float3*)(coords+3*d3) : make_float3(9,9,9);
  #define EDGE_EMIT(vv, aa, bb, ss, dd)                                        \
    if (vv){                                                                   \
      float dx = bb.x-aa.x, dy = bb.y-aa.y, dz = bb.z-aa.z;                    \
      float r2 = dx*dx + dy*dy + dz*dz + 1e-8f;                                \
      if (r2 < RMAX*RMAX){                                                     \
        float r = sqrtf(r2);                                                   \
        unsigned u = (__float_as_uint(r) & ~3u) | (unsigned)species[ss];       \
        int pos = atomicAdd(&hist[dd], 1);                                     \
        if (pos < DEGCAP) pay[(size_t)(dd) * DEGCAP + pos] = u;                \
      }                                                                        \
    }
  EDGE_EMIT(v0, a0, b0, s0, d0)
  EDGE_EMIT(v1, a1, b1, s1, d1)
  EDGE_EMIT(v2, a2, b2, s2, d2)
  EDGE_EMIT(v3, a3, b3, s3, d3)
  #undef EDGE_EMIT
}

// ---------------- fused gather + node tail: 8 lanes per node ----------------
// Round-9 post-mortem: 224 ds_bpermute/lane + serial payload->tab chains were
// the stall source (VALUBusy 33%, wall 145us vs ~22us issue floor). This
// version: (a) wave-synchronous LDS exchange (publish own slice, ds_read_b128
// others; strictly intra-wave lockstep -> no barriers), 63 DS ops vs 224;
// (b) 8 payloads prefetched as 2x uint4 (DEGCAP=48 makes it always safe),
// fully unrolled compile-time-indexed steps so tab loads issue together.
__global__ void __launch_bounds__(256, 8) k_gather_node(
    const int* __restrict__ hist, const unsigned* __restrict__ pay,
    const float* __restrict__ tab, const float* __restrict__ sctab,
    const int* __restrict__ species,
    const float* __restrict__ W2s, const float* __restrict__ Wfin,
    const float* __restrict__ Wr,  const float* __restrict__ Wm1,
    const float* __restrict__ Wm2, const float* __restrict__ Wm3,
    float* __restrict__ out, int N){
  const float s_16s32 = 0.0625f * 0.17677669529663687f;
  const float s_s64   = 0.125f;
  const float s_s32   = 0.17677669529663687f;
  __shared__ float aex[4][8][40];   // per-wave a-exchange rows (stride 40: 2-way-free reads)
  __shared__ float sex[4][8][68];   // per-wave 64-wide exchange rows (stride 68)

  int tid = threadIdx.x;
  int w   = tid >> 6;
  int ln  = tid & 63;
  int nl  = ln >> 3;    // node-in-wave
  int sub = ln & 7;
  int gid = blockIdx.x * 256 + tid;
  int n = gid >> 3;
  if (n >= N) return;
  int k4 = sub * 4;
  int k8 = sub * 8;
  float* arow = aex[w][nl];
  float* srow = sex[w][nl];

  // ---- transposed gather: lane sums components [k4,k4+4) over ALL edges ----
  float4 accA = make_float4(0.f, 0.f, 0.f, 0.f);
  int cnt = min(hist[n], DEGCAP);
  const unsigned* prow = pay + (size_t)n * DEGCAP;
  const uint4* p4 = (const uint4*)prow;
  uint4 u0 = p4[0], u1 = p4[1];     // always in-bounds (DEGCAP slots exist)
  #define GSTEP(UVAL, EIDX)                                                    \
    if ((EIDX) < cnt){                                                         \
      unsigned uu = (UVAL);                                                    \
      int cc = (int)(uu & 3u);                                                 \
      float r = __uint_as_float(uu & ~3u);                                     \
      float tt = r * ((float)NTAB / RMAX);                                     \
      int i0 = min((int)tt, NTAB - 1);                                         \
      float f = tt - (float)i0;                                                \
      const float4* r0 = (const float4*)(tab + ((size_t)i0*4 + cc)*32) + sub;  \
      float4 p = r0[0], q = r0[32];                                            \
      accA.x += p.x + f*(q.x - p.x);                                           \
      accA.y += p.y + f*(q.y - p.y);                                           \
      accA.z += p.z + f*(q.z - p.z);                                           \
      accA.w += p.w + f*(q.w - p.w);                                           \
    }
  GSTEP(u0.x, 0) GSTEP(u0.y, 1) GSTEP(u0.z, 2) GSTEP(u0.w, 3)
  GSTEP(u1.x, 4) GSTEP(u1.y, 5) GSTEP(u1.z, 6) GSTEP(u1.w, 7)
  for (int e = 8; e < cnt; ++e){ GSTEP(prow[e], e) }
  #undef GSTEP

  int c = species[n];

  // publish a-slice; wave-lockstep + per-wave-ordered LDS => no barrier
  *(float4*)&arow[k4] = accA;

  // ---- L1: S[64] = normact(a @ W2s * s + sctab[c]); lane owns [k8,k8+8) ----
  float acc8[8];
  #pragma unroll
  for (int t = 0; t < 8; ++t) acc8[t] = 0.f;
  #pragma unroll
  for (int jq = 0; jq < 8; ++jq){
    float4 a4 = *(const float4*)&arow[jq*4];
    #pragma unroll
    for (int t = 0; t < 4; ++t){
      float av = (t==0)?a4.x:(t==1)?a4.y:(t==2)?a4.z:a4.w;
      const int j = jq*4 + t;
      const float4 w0 = *(const float4*)&W2s[j*64 + k8];
      const float4 w1 = *(const float4*)&W2s[j*64 + k8 + 4];
      acc8[0] += av*w0.x; acc8[1] += av*w0.y; acc8[2] += av*w0.z; acc8[3] += av*w0.w;
      acc8[4] += av*w1.x; acc8[5] += av*w1.y; acc8[6] += av*w1.z; acc8[7] += av*w1.w;
    }
  }
  float4 s0v, s1v;
  {
    const float4 b0 = *(const float4*)&sctab[c*64 + k8];
    const float4 b1 = *(const float4*)&sctab[c*64 + k8 + 4];
    s0v.x = normact(acc8[0]*s_16s32 + b0.x);
    s0v.y = normact(acc8[1]*s_16s32 + b0.y);
    s0v.z = normact(acc8[2]*s_16s32 + b0.z);
    s0v.w = normact(acc8[3]*s_16s32 + b0.w);
    s1v.x = normact(acc8[4]*s_16s32 + b1.x);
    s1v.y = normact(acc8[5]*s_16s32 + b1.y);
    s1v.z = normact(acc8[6]*s_16s32 + b1.z);
    s1v.w = normact(acc8[7]*s_16s32 + b1.w);
  }
  *(float4*)&srow[k8]     = s0v;
  *(float4*)&srow[k8 + 4] = s1v;

  // ---- L2: y[32] = normact(S @ Wfin * s_s64); lane owns [k4,k4+4) ----
  float4 acc4 = make_float4(0.f, 0.f, 0.f, 0.f);
  #pragma unroll
  for (int jq = 0; jq < 16; ++jq){
    float4 s4 = *(const float4*)&srow[jq*4];
    #pragma unroll
    for (int t = 0; t < 4; ++t){
      float sv = (t==0)?s4.x:(t==1)?s4.y:(t==2)?s4.z:s4.w;
      const int j = jq*4 + t;
      const float4 wv = *(const float4*)&Wfin[j*32 + k4];
      acc4.x += sv*wv.x; acc4.y += sv*wv.y; acc4.z += sv*wv.z; acc4.w += sv*wv.w;
    }
  }
  float4 yv;
  yv.x = normact(acc4.x*s_s64); yv.y = normact(acc4.y*s_s64);
  yv.z = normact(acc4.z*s_s64); yv.w = normact(acc4.w*s_s64);
  *(float4*)&srow[k4] = yv;   // all lanes done reading S (lockstep)

  // ---- L3: y2[32] = y + normact(y @ Wr * s_s32); lane owns [k4,k4+4) ----
  acc4 = make_float4(0.f, 0.f, 0.f, 0.f);
  #pragma unroll
  for (int jq = 0; jq < 8; ++jq){
    float4 y4 = *(const float4*)&srow[jq*4];
    #pragma unroll
    for (int t = 0; t < 4; ++t){
      float yvv = (t==0)?y4.x:(t==1)?y4.y:(t==2)?y4.z:y4.w;
      const int j = jq*4 + t;
      const float4 wv = *(const float4*)&Wr[j*32 + k4];
      acc4.x += yvv*wv.x; acc4.y += yvv*wv.y; acc4.z += yvv*wv.z; acc4.w += yvv*wv.w;
    }
  }
  float4 y2v;
  y2v.x = yv.x + normact(acc4.x*s_s32);
  y2v.y = yv.y + normact(acc4.y*s_s32);
  y2v.z = yv.z + normact(acc4.z*s_s32);
  y2v.w = yv.w + normact(acc4.w*s_s32);
  *(float4*)&srow[k4] = y2v;  // all lanes done reading y (lockstep)

  // ---- L4: h[64] = tanh(y2 @ Wm1 * s_s32); lane owns [k8,k8+8) ----
  #pragma unroll
  for (int t = 0; t < 8; ++t) acc8[t] = 0.f;
  #pragma unroll
  for (int jq = 0; jq < 8; ++jq){
    float4 y4 = *(const float4*)&srow[jq*4];
    #pragma unroll
    for (int t = 0; t < 4; ++t){
      float yvv = (t==0)?y4.x:(t==1)?y4.y:(t==2)?y4.z:y4.w;
      const int j = jq*4 + t;
      const float4 w0 = *(const float4*)&Wm1[j*64 + k8];
      const float4 w1 = *(const float4*)&Wm1[j*64 + k8 + 4];
      acc8[0] += yvv*w0.x; acc8[1] += yvv*w0.y; acc8[2] += yvv*w0.z; acc8[3] += yvv*w0.w;
      acc8[4] += yvv*w1.x; acc8[5] += yvv*w1.y; acc8[6] += yvv*w1.z; acc8[7] += yvv*w1.w;
    }
  }
  float4 h0v, h1v;
  h0v.x = tanh_fast(acc8[0]*s_s32); h0v.y = tanh_fast(acc8[1]*s_s32);
  h0v.z = tanh_fast(acc8[2]*s_s32); h0v.w = tanh_fast(acc8[3]*s_s32);
  h1v.x = tanh_fast(acc8[4]*s_s32); h1v.y = tanh_fast(acc8[5]*s_s32);
  h1v.z = tanh_fast(acc8[6]*s_s32); h1v.w = tanh_fast(acc8[7]*s_s32);
  *(float4*)&srow[k8]     = h0v;  // all lanes done reading y2 (lockstep)
  *(float4*)&srow[k8 + 4] = h1v;

  // ---- L5: g[32] = tanh(h @ Wm2 * s_s64); fold dot with Wm3 ----
  acc4 = make_float4(0.f, 0.f, 0.f, 0.f);
  #pragma unroll
  for (int jq = 0; jq < 16; ++jq){
    float4 h4 = *(const float4*)&srow[jq*4];
    #pragma unroll
    for (int t = 0; t < 4; ++t){
      float hv = (t==0)?h4.x:(t==1)?h4.y:(t==2)?h4.z:h4.w;
      const int j = jq*4 + t;
      const float4 wv = *(const float4*)&Wm2[j*32 + k4];
      acc4.x += hv*wv.x; acc4.y += hv*wv.y; acc4.z += hv*wv.z; acc4.w += hv*wv.w;
    }
  }
  float acc = tanh_fast(acc4.x*s_s64) * Wm3[k4 + 0]
            + tanh_fast(acc4.y*s_s64) * Wm3[k4 + 1]
            + tanh_fast(acc4.z*s_s64) * Wm3[k4 + 2]
            + tanh_fast(acc4.w*s_s64) * Wm3[k4 + 3];
  acc += __shfl_xor(acc, 1);
  acc += __shfl_xor(acc, 2);
  acc += __shfl_xor(acc, 4);
  if (sub == 0) out[n] = acc * s_s32;
}

extern "C" void kernel_launch(void* const* d_in, const int* in_sizes, int n_in,
                              void* d_out, int out_size, void* d_ws, size_t ws_size,
                              hipStream_t stream) {
  const float* coords   = (const float*)d_in[0];
  const int*   species  = (const int*)  d_in[1];
  const int*   ei       = (const int*)  d_in[2];
  const float* Wna      = (const float*)d_in[4];
  const float* Wlin1    = (const float*)d_in[5];
  const float* Wr1      = (const float*)d_in[6];
  const float* Wr2      = (const float*)d_in[7];
  const float* Wr3      = (const float*)d_in[8];
  const float* W2s      = (const float*)d_in[9];
  const float* Wsc      = (const float*)d_in[11];
  const float* Wfin     = (const float*)d_in[12];
  const float* Wr       = (const float*)d_in[13];
  const float* Wm1      = (const float*)d_in[14];
  const float* Wm2      = (const float*)d_in[15];
  const float* Wm3      = (const float*)d_in[16];
  float* out = (float*)d_out;

  const int N = in_sizes[1];
  const int E = in_sizes[2] / 2;

  char* ws = (char*)d_ws;
  size_t offX1  = 0;                                 // x1tab 512B
  size_t offSC  = offX1 + 512;                       // sctab 1024B
  size_t offTAB = offSC + 1024;                      // tab (NTAB+2)*128 f32 (~2.1MB)
  size_t offH   = offTAB + (size_t)(NTAB+2)*128*4;   // hist [N] int
  size_t offP   = offH + (size_t)N*4;                // pay  [N*DEGCAP] u32 (~19.2MB)

  float*    x1tab = (float*)(ws + offX1);
  float*    sctab = (float*)(ws + offSC);
  float*    tab   = (float*)(ws + offTAB);
  int*      hist  = (int*)  (ws + offH);
  unsigned* pay   = (unsigned*)(ws + offP);

  hipMemsetAsync(hist, 0, (size_t)N*4, stream);

  k_pre<<<1, 256, 0, stream>>>(Wna, Wlin1, Wsc, x1tab, sctab);
  k_tab<<<(NTAB + 256) / 256, 256, 0, stream>>>(Wr1, Wr2, Wr3, x1tab, tab);
  k_edges<<<(E + 1023) / 1024, 256, 0, stream>>>(coords, ei, species, hist, pay, E);
  k_gather_node<<<((size_t)N*8 + 255) / 256, 256, 0, stream>>>(
      hist, pay, tab, sctab, species, W2s, Wfin, Wr, Wm1, Wm2, Wm3, out, N);
}

// Round 11
// 162.669 us; speedup vs baseline: 1.4264x; 1.4264x over previous
//
#include <hip/hip_runtime.h>
#include <math.h>

#define RMAX 4.0f
#define NTAB 4096    // intervals over [0,4); rows 0..4096 built (+pad)
#define DEGCAP 48    // max live in-degree bucket capacity (P(exceed) ~ 1e-11)
#define TROW 65      // per-lane LDS activation row stride (odd -> 2-way banks, free)

__device__ __forceinline__ float tanh_fast(float x){
  float e = __expf(2.0f * x);
  return 1.0f - 2.0f / (e + 1.0f);
}
__device__ __forceinline__ float normact(float s){
  float ns = fabsf(s);
  return s * tanh_fast(ns) / (ns + 1e-8f);
}

// ---------------- precompute per-species tables ----------------
__global__ void k_pre(const float* __restrict__ Wna, const float* __restrict__ Wlin1,
                      const float* __restrict__ Wsc,
                      float* __restrict__ x1tab, float* __restrict__ sctab){
  int id = threadIdx.x;
  if (id < 128){
    int c = id >> 5, j = id & 31;
    float acc = 0.f;
    for (int i = 0; i < 32; ++i) acc += Wna[c*32+i] * Wlin1[i*32+j];
    x1tab[id] = acc * (0.5f * 0.17677669529663687f);
  }
  if (id < 256){
    int c = id >> 6, k = id & 63;
    float acc = 0.f;
    for (int i = 0; i < 32; ++i) acc += Wna[c*32+i] * Wsc[(i*4+c)*64+k];
    sctab[id] = acc * (0.5f * 0.08838834764831843f);
  }
}

// ---------------- build radial table: tab[(i*4+c)*32+g] = w(r_i)[g]*x1tab[c][g] ----
__global__ void __launch_bounds__(256) k_tab(
    const float* __restrict__ Wr1, const float* __restrict__ Wr2,
    const float* __restrict__ Wr3, const float* __restrict__ x1tab,
    float* __restrict__ tab){
  __shared__ float sW1[8*64];
  __shared__ float sW2T[64*64];
  __shared__ float sW3[64*32];
  __shared__ float sX1[4*32];
  int t = threadIdx.x;
  for (int i = t; i < 512; i += 256) sW1[i] = Wr1[i] * 0.3535533905932738f;
  for (int i = t; i < 4096; i += 256){ int rr = i >> 6, cc = i & 63; sW2T[cc*64+rr] = Wr2[i] * 0.125f; }
  for (int i = t; i < 2048; i += 256){ int rr = i >> 5, cc = i & 31; sW3[i] = Wr3[rr*64+cc] * 0.125f; }
  for (int i = t; i < 128; i += 256) sX1[i] = x1tab[i];
  __syncthreads();
  int i = blockIdx.x * 256 + t;
  if (i > NTAB) return;
  float r = fmaxf((float)i * (RMAX / (float)NTAB), 1e-6f);

  float u = r * 0.25f;
  float u2 = u*u, u4 = u2*u2, u6 = u4*u2;
  float fc = 1.0f + u6 * (-28.0f + u * (48.0f - 21.0f * u));
  float pref = 0.5f / r * fc;
  float ea[8];
  #pragma unroll
  for (int k = 1; k <= 8; ++k) ea[k-1] = __sinf(0.78539816339744831f * r * (float)k) * pref;

  float h1[64];
  #pragma unroll
  for (int j = 0; j < 64; j += 4){
    float ax = 0.f, ay = 0.f, az = 0.f, aw = 0.f;
    #pragma unroll
    for (int k = 0; k < 8; ++k){
      const float4 w4 = *(const float4*)&sW1[k*64 + j];
      ax += ea[k]*w4.x; ay += ea[k]*w4.y; az += ea[k]*w4.z; aw += ea[k]*w4.w;
    }
    h1[j]   = tanh_fast(ax); h1[j+1] = tanh_fast(ay);
    h1[j+2] = tanh_fast(az); h1[j+3] = tanh_fast(aw);
  }

  float wsx[8], wsy[8], wsz[8], wsw[8];
  #pragma unroll
  for (int g = 0; g < 8; ++g){ wsx[g]=0.f; wsy[g]=0.f; wsz[g]=0.f; wsw[g]=0.f; }
  for (int j = 0; j < 64; ++j){
    float ax = 0.f, ay = 0.f, az = 0.f, aw = 0.f;
    #pragma unroll
    for (int k = 0; k < 64; k += 4){
      const float4 w4 = *(const float4*)&sW2T[j*64 + k];
      ax += h1[k]*w4.x; ay += h1[k+1]*w4.y; az += h1[k+2]*w4.z; aw += h1[k+3]*w4.w;
    }
    float tj = tanh_fast(ax + ay + az + aw);
    #pragma unroll
    for (int g = 0; g < 8; ++g){
      const float4 w4 = *(const float4*)&sW3[j*32 + g*4];
      wsx[g] += tj*w4.x; wsy[g] += tj*w4.y; wsz[g] += tj*w4.z; wsw[g] += tj*w4.w;
    }
  }

  #pragma unroll
  for (int c = 0; c < 4; ++c){
    float* row = tab + ((size_t)i*4 + c)*32;
    #pragma unroll
    for (int g = 0; g < 8; ++g){
      const float4 xv = *(const float4*)&sX1[c*32 + g*4];
      row[g*4+0] = wsx[g]*xv.x;
      row[g*4+1] = wsy[g]*xv.y;
      row[g*4+2] = wsz[g]*xv.z;
      row[g*4+3] = wsw[g]*xv.w;
    }
  }
}

// ---------------- single-pass bucketed edge build (1 edge/thread) ----------------
// pay[d*DEGCAP + slot] = r packed with species(src) in low 2 bits
__global__ void __launch_bounds__(256) k_edges(
    const float* __restrict__ coords, const int* __restrict__ ei,
    const int* __restrict__ species, int* __restrict__ hist,
    unsigned* __restrict__ pay, int E){
  int i = blockIdx.x * blockDim.x + threadIdx.x;
  if (i >= E) return;
  int s = ei[i], d = ei[E + i];
  float3 cs = *(const float3*)(coords + 3*s);
  float3 cd = *(const float3*)(coords + 3*d);
  float dx = cd.x - cs.x, dy = cd.y - cs.y, dz = cd.z - cs.z;
  float r2 = dx*dx + dy*dy + dz*dz + 1e-8f;
  if (r2 >= RMAX*RMAX) return;           // fcut=0 -> msg exactly 0
  float r = sqrtf(r2);
  unsigned u = (__float_as_uint(r) & ~3u) | (unsigned)species[s];
  int pos = atomicAdd(&hist[d], 1);
  if (pos < DEGCAP) pay[(size_t)d * DEGCAP + pos] = u;
}

// ---------------- gather only: 8 lanes per node -> agg[N][32] ----------------
__global__ void __launch_bounds__(256, 8) k_gather(
    const int* __restrict__ hist, const unsigned* __restrict__ pay,
    const float* __restrict__ tab, float* __restrict__ agg, int N){
  int gid = blockIdx.x * 256 + threadIdx.x;
  int n = gid >> 3;
  if (n >= N) return;
  int sub = gid & 7;
  float4 accA = make_float4(0.f, 0.f, 0.f, 0.f);
  int cnt = min(hist[n], DEGCAP);
  const unsigned* prow = pay + (size_t)n * DEGCAP;
  const uint4* p4 = (const uint4*)prow;
  uint4 u0 = p4[0], u1 = p4[1];     // always in-bounds (DEGCAP slots exist)
  #define GSTEP(UVAL, EIDX)                                                    \
    if ((EIDX) < cnt){                                                         \
      unsigned uu = (UVAL);                                                    \
      int cc = (int)(uu & 3u);                                                 \
      float r = __uint_as_float(uu & ~3u);                                     \
      float tt = r * ((float)NTAB / RMAX);                                     \
      int i0 = min((int)tt, NTAB - 1);                                         \
      float f = tt - (float)i0;                                                \
      const float4* r0 = (const float4*)(tab + ((size_t)i0*4 + cc)*32) + sub;  \
      float4 p = r0[0], q = r0[32];                                            \
      accA.x += p.x + f*(q.x - p.x);                                           \
      accA.y += p.y + f*(q.y - p.y);                                           \
      accA.z += p.z + f*(q.z - p.z);                                           \
      accA.w += p.w + f*(q.w - p.w);                                           \
    }
  GSTEP(u0.x, 0) GSTEP(u0.y, 1) GSTEP(u0.z, 2) GSTEP(u0.w, 3)
  GSTEP(u1.x, 4) GSTEP(u1.y, 5) GSTEP(u1.z, 6) GSTEP(u1.w, 7)
  for (int e = 8; e < cnt; ++e){ GSTEP(prow[e], e) }
  #undef GSTEP
  *(float4*)&agg[(size_t)n * 32 + sub * 4] = accA;
}

// ---------------- node tail: ONE NODE PER LANE, weights via SGPR ----------------
// Round-10 post-mortem: fused kernel was weight-load bound (~3.6GB of per-lane
// 16B weight reads through L1/L2 ~= 100us at L2 BW; DS-reduction was neutral).
// Here every weight index is lane-invariant -> compiler scalarizes to s_load
// (one read serves 64 nodes, traffic /64). Per-lane activations live in a
// PRIVATE LDS row (stride 65 floats: bank=(lane+j)%32 -> 2-way, free; no
// barriers needed) so j-loops avoid dynamic register indexing (rule #20).
// Accumulators are static-indexed registers only.
__global__ void __launch_bounds__(256) k_tail(
    const float* __restrict__ agg, const float* __restrict__ sctab,
    const int* __restrict__ species,
    const float* __restrict__ W2s, const float* __restrict__ Wfin,
    const float* __restrict__ Wr,  const float* __restrict__ Wm1,
    const float* __restrict__ Wm2, const float* __restrict__ Wm3,
    float* __restrict__ out, int N){
  const float s_16s32 = 0.0625f * 0.17677669529663687f;
  const float s_s64   = 0.125f;
  const float s_s32   = 0.17677669529663687f;
  __shared__ float act[256 * TROW];   // 66.56 KB, per-lane private rows
  float* row = &act[threadIdx.x * TROW];
  int n = blockIdx.x * 256 + threadIdx.x;
  if (n >= N) return;
  int c = species[n];

  // load a[32] (fat per-lane row read, L2-resident) -> LDS row
  {
    const float4* ar = (const float4*)(agg + (size_t)n * 32);
    #pragma unroll
    for (int q = 0; q < 8; ++q){
      float4 v = ar[q];
      row[q*4+0] = v.x; row[q*4+1] = v.y; row[q*4+2] = v.z; row[q*4+3] = v.w;
    }
  }

  // ---- L1: S[64] = normact(a @ W2s * s + sctab[c]) ----
  float S[64];
  #pragma unroll
  for (int k = 0; k < 64; ++k) S[k] = 0.f;
  #pragma unroll 4
  for (int j = 0; j < 32; ++j){
    float av = row[j];
    #pragma unroll
    for (int k = 0; k < 64; ++k) S[k] += av * W2s[j*64 + k];
  }
  #pragma unroll
  for (int k = 0; k < 64; ++k) S[k] = normact(S[k]*s_16s32 + sctab[c*64 + k]);
  #pragma unroll
  for (int k = 0; k < 64; ++k) row[k] = S[k];

  // ---- L2: y[32] = normact(S @ Wfin * s_s64) ----
  float y[32];
  #pragma unroll
  for (int k = 0; k < 32; ++k) y[k] = 0.f;
  #pragma unroll 4
  for (int j = 0; j < 64; ++j){
    float sv = row[j];
    #pragma unroll
    for (int k = 0; k < 32; ++k) y[k] += sv * Wfin[j*32 + k];
  }
  #pragma unroll
  for (int k = 0; k < 32; ++k) y[k] = normact(y[k]*s_s64);
  #pragma unroll
  for (int k = 0; k < 32; ++k) row[k] = y[k];

  // ---- L3: y2[32] = y + normact(y @ Wr * s_s32) ----
  float y2[32];
  #pragma unroll
  for (int k = 0; k < 32; ++k) y2[k] = 0.f;
  #pragma unroll 4
  for (int j = 0; j < 32; ++j){
    float yv = row[j];
    #pragma unroll
    for (int k = 0; k < 32; ++k) y2[k] += yv * Wr[j*32 + k];
  }
  #pragma unroll
  for (int k = 0; k < 32; ++k) y2[k] = y[k] + normact(y2[k]*s_s32);
  #pragma unroll
  for (int k = 0; k < 32; ++k) row[k] = y2[k];

  // ---- L4: h[64] = tanh(y2 @ Wm1 * s_s32) ----
  #pragma unroll
  for (int k = 0; k < 64; ++k) S[k] = 0.f;
  #pragma unroll 4
  for (int j = 0; j < 32; ++j){
    float yv = row[j];
    #pragma unroll
    for (int k = 0; k < 64; ++k) S[k] += yv * Wm1[j*64 + k];
  }
  #pragma unroll
  for (int k = 0; k < 64; ++k) S[k] = tanh_fast(S[k]*s_s32);
  #pragma unroll
  for (int k = 0; k < 64; ++k) row[k] = S[k];

  // ---- L5: g[32] = tanh(h @ Wm2 * s_s64); out = g . Wm3 * s_s32 ----
  float g[32];
  #pragma unroll
  for (int k = 0; k < 32; ++k) g[k] = 0.f;
  #pragma unroll 4
  for (int j = 0; j < 64; ++j){
    float hv = row[j];
    #pragma unroll
    for (int k = 0; k < 32; ++k) g[k] += hv * Wm2[j*32 + k];
  }
  float acc = 0.f;
  #pragma unroll
  for (int k = 0; k < 32; ++k) acc += tanh_fast(g[k]*s_s64) * Wm3[k];
  out[n] = acc * s_s32;
}

extern "C" void kernel_launch(void* const* d_in, const int* in_sizes, int n_in,
                              void* d_out, int out_size, void* d_ws, size_t ws_size,
                              hipStream_t stream) {
  const float* coords   = (const float*)d_in[0];
  const int*   species  = (const int*)  d_in[1];
  const int*   ei       = (const int*)  d_in[2];
  const float* Wna      = (const float*)d_in[4];
  const float* Wlin1    = (const float*)d_in[5];
  const float* Wr1      = (const float*)d_in[6];
  const float* Wr2      = (const float*)d_in[7];
  const float* Wr3      = (const float*)d_in[8];
  const float* W2s      = (const float*)d_in[9];
  const float* Wsc      = (const float*)d_in[11];
  const float* Wfin     = (const float*)d_in[12];
  const float* Wr       = (const float*)d_in[13];
  const float* Wm1      = (const float*)d_in[14];
  const float* Wm2      = (const float*)d_in[15];
  const float* Wm3      = (const float*)d_in[16];
  float* out = (float*)d_out;

  const int N = in_sizes[1];
  const int E = in_sizes[2] / 2;

  char* ws = (char*)d_ws;
  size_t offX1  = 0;                                 // x1tab 512B
  size_t offSC  = offX1 + 512;                       // sctab 1024B
  size_t offTAB = offSC + 1024;                      // tab (NTAB+2)*128 f32 (~2.1MB)
  size_t offH   = offTAB + (size_t)(NTAB+2)*128*4;   // hist [N] int
  size_t offP   = offH + (size_t)N*4;                // pay  [N*DEGCAP] u32 (~19.2MB)
  size_t offA   = offP + (size_t)N*DEGCAP*4;         // agg  [N*32] f32 (12.8MB)

  float*    x1tab = (float*)(ws + offX1);
  float*    sctab = (float*)(ws + offSC);
  float*    tab   = (float*)(ws + offTAB);
  int*      hist  = (int*)  (ws + offH);
  unsigned* pay   = (unsigned*)(ws + offP);
  float*    agg   = (float*)(ws + offA);

  hipMemsetAsync(hist, 0, (size_t)N*4, stream);

  k_pre<<<1, 256, 0, stream>>>(Wna, Wlin1, Wsc, x1tab, sctab);
  k_tab<<<(NTAB + 256) / 256, 256, 0, stream>>>(Wr1, Wr2, Wr3, x1tab, tab);
  k_edges<<<(E + 255) / 256, 256, 0, stream>>>(coords, ei, species, hist, pay, E);
  k_gather<<<((size_t)N*8 + 255) / 256, 256, 0, stream>>>(hist, pay, tab, agg, N);
  k_tail<<<(N + 255) / 256, 256, 0, stream>>>(agg, sctab, species, W2s, Wfin,
                                              Wr, Wm1, Wm2, Wm3, out, N);
}